// Round 10
// baseline (396.481 us; speedup 1.0000x reference)
//
#include <hip/hip_runtime.h>
#include <hip/hip_bf16.h>

typedef __hip_bfloat16 bf16;
typedef short bf16x8 __attribute__((ext_vector_type(8)));
typedef short bf16x4 __attribute__((ext_vector_type(4)));
typedef float f32x4 __attribute__((ext_vector_type(4)));
typedef unsigned int u32x4 __attribute__((ext_vector_type(4)));
typedef unsigned int u32x2 __attribute__((ext_vector_type(2)));

#if __has_builtin(__builtin_amdgcn_permlane16_swap) && \
    __has_builtin(__builtin_amdgcn_permlane32_swap)
#define HAVE_PERMLANE_SWAP 1
#else
#define HAVE_PERMLANE_SWAP 0
#endif

__device__ __forceinline__ float gelu_f(float x) {
  return 0.5f * x * (1.f + erff(x * 0.70710678118654752f));
}

__device__ __forceinline__ unsigned short f2bfu(float f) {
  bf16 h = __float2bfloat16(f);
  unsigned short u;
  __builtin_memcpy(&u, &h, 2);
  return u;
}

// async 16B/lane global->LDS; lds dest is wave-uniform base + lane*16
__device__ __forceinline__ void load16_lds(const bf16* g, bf16* l) {
  __builtin_amdgcn_global_load_lds(
      (const __attribute__((address_space(1))) unsigned int*)g,
      (__attribute__((address_space(3))) unsigned int*)l, 16, 0, 0);
}

// ---------------- weight transpose + cast: src fp32 [R][C] -> dst bf16 [C][R]
__global__ __launch_bounds__(256) void transpose_cast(
    const float* __restrict__ src, bf16* __restrict__ dst, int R, int C) {
  __shared__ float tile[32][33];
  int tx = threadIdx.x & 31, ty = threadIdx.x >> 5;  // 32 x 8
  int r0 = blockIdx.y * 32, c0 = blockIdx.x * 32;
  #pragma unroll
  for (int i = ty; i < 32; i += 8)
    tile[i][tx] = src[(size_t)(r0 + i) * C + (c0 + tx)];
  __syncthreads();
  #pragma unroll
  for (int i = ty; i < 32; i += 8)
    dst[(size_t)(c0 + i) * R + (r0 + tx)] = __float2bfloat16(tile[tx][i]);
}

// batched 1024x1024 transpose for Wq/Wk/Wv/Wo in ONE launch (z = 0..3)
__global__ __launch_bounds__(256) void transpose_cast_qkvo(
    const float* __restrict__ s0, const float* __restrict__ s1,
    const float* __restrict__ s2, const float* __restrict__ s3,
    bf16* __restrict__ dqkv, bf16* __restrict__ dwo) {
  __shared__ float tile[32][33];
  const int z = blockIdx.z;
  const float* src = z == 0 ? s0 : z == 1 ? s1 : z == 2 ? s2 : s3;
  bf16* dst = z < 3 ? dqkv + (size_t)z * 1024 * 1024 : dwo;
  int tx = threadIdx.x & 31, ty = threadIdx.x >> 5;  // 32 x 8
  int r0 = blockIdx.y * 32, c0 = blockIdx.x * 32;
  #pragma unroll
  for (int i = ty; i < 32; i += 8)
    tile[i][tx] = src[(size_t)(r0 + i) * 1024 + (c0 + tx)];
  __syncthreads();
  #pragma unroll
  for (int i = ty; i < 32; i += 8)
    dst[(size_t)(c0 + i) * 1024 + (r0 + tx)] = __float2bfloat16(tile[tx][i]);
}

// ---------------- LayerNorm: x fp32 [rows][1024] -> y bf16, one block per row
__global__ __launch_bounds__(256) void ln_kernel(
    const float* __restrict__ x, const float* __restrict__ g,
    const float* __restrict__ b, bf16* __restrict__ y) {
  int row = blockIdx.x;
  int t = threadIdx.x;
  const float4* xr = (const float4*)(x + (size_t)row * 1024);
  float4 v = xr[t];
  float s = v.x + v.y + v.z + v.w;
  float ss = v.x * v.x + v.y * v.y + v.z * v.z + v.w * v.w;
  #pragma unroll
  for (int off = 32; off >= 1; off >>= 1) {
    s += __shfl_xor(s, off);
    ss += __shfl_xor(ss, off);
  }
  __shared__ float red[8];
  int wv = t >> 6;
  if ((t & 63) == 0) { red[wv] = s; red[4 + wv] = ss; }
  __syncthreads();
  float S = red[0] + red[1] + red[2] + red[3];
  float SS = red[4] + red[5] + red[6] + red[7];
  float mu = S * (1.f / 1024.f);
  float var = SS * (1.f / 1024.f) - mu * mu;
  float inv = rsqrtf(var + 1e-5f);
  float4 gv = ((const float4*)g)[t];
  float4 bv = ((const float4*)b)[t];
  ushort4 o;
  o.x = f2bfu((v.x - mu) * inv * gv.x + bv.x);
  o.y = f2bfu((v.y - mu) * inv * gv.y + bv.y);
  o.z = f2bfu((v.z - mu) * inv * gv.z + bv.z);
  o.w = f2bfu((v.w - mu) * inv * gv.w + bv.w);
  ((ushort4*)(y + (size_t)row * 1024))[t] = o;
}

// ---------------- 128x128 GEMM (m97 structure) — kept for the Wo projection
// EPI 3: fp32 out = val + resid
// XCD-bijective block remap (grid.x*grid.y % 8 == 0 at all call sites).
template <int EPI>
__global__ __launch_bounds__(256) void gemm_bf16(
    const bf16* __restrict__ A, const bf16* __restrict__ Bt,
    const float* __restrict__ bias0, const float* __restrict__ resid,
    void* __restrict__ C0, int M, int N, int K) {
  __shared__ __align__(16) bf16 As[2][128 * 32];
  __shared__ __align__(16) bf16 Bs[2][128 * 32];
  const int t = threadIdx.x, lane = t & 63, w = t >> 6;
  const int wm = (w >> 1) * 64, wn = (w & 1) * 64;

  const int gx = gridDim.x;
  const int L = blockIdx.y * gx + blockIdx.x;        // hw dispatch order
  const int nwg = gx * gridDim.y;
  const int wg = (L & 7) * (nwg >> 3) + (L >> 3);    // XCD-contiguous
  const int m0 = (wg / gx) * 128, n0 = (wg % gx) * 128;

  const int srow = lane >> 2;
  const int sgrp = lane & 3;
  f32x4 acc[4][4] = {};

  const bf16* Abase = A + (size_t)m0 * K;
  const bf16* Bbase = Bt + (size_t)n0 * K;

  auto stage = [&](int buf, int kt) {
    #pragma unroll
    for (int c = 0; c < 2; ++c) {
      int row = w * 32 + c * 16 + srow;
      int sw = (row & 3) ^ ((row >> 2) & 3);
      int gg = sgrp ^ sw;
      const bf16* ga = Abase + (size_t)row * K + kt + gg * 8;
      const bf16* gb = Bbase + (size_t)row * K + kt + gg * 8;
      load16_lds(ga, &As[buf][(w * 32 + c * 16) * 32]);
      load16_lds(gb, &Bs[buf][(w * 32 + c * 16) * 32]);
    }
  };

  const int q8 = (((lane >> 4) ^ (lane & 3) ^ ((lane >> 2) & 3))) * 8;
  const int fr = lane & 15;

  const int nk = K >> 5;
  stage(0, 0);
  for (int i = 0; i < nk; ++i) {
    const int cur = i & 1;
    __syncthreads();
    if (i + 1 < nk) stage(cur ^ 1, (i + 1) << 5);
    bf16x8 af[4], bfr[4];
    #pragma unroll
    for (int mc = 0; mc < 4; ++mc)
      af[mc] = *(const bf16x8*)&As[cur][(wm + mc * 16 + fr) * 32 + q8];
    #pragma unroll
    for (int nc = 0; nc < 4; ++nc)
      bfr[nc] = *(const bf16x8*)&Bs[cur][(wn + nc * 16 + fr) * 32 + q8];
    #pragma unroll
    for (int mc = 0; mc < 4; ++mc)
      #pragma unroll
      for (int nc = 0; nc < 4; ++nc)
        acc[mc][nc] = __builtin_amdgcn_mfma_f32_16x16x32_bf16(
            af[mc], bfr[nc], acc[mc][nc], 0, 0, 0);
  }

  #pragma unroll
  for (int mc = 0; mc < 4; ++mc) {
    #pragma unroll
    for (int reg = 0; reg < 4; ++reg) {
      int m = m0 + wm + mc * 16 + ((lane >> 4) << 2) + reg;
      #pragma unroll
      for (int nc = 0; nc < 4; ++nc) {
        int n = n0 + wn + nc * 16 + (lane & 15);
        float val = acc[mc][nc][reg] + bias0[n];
        size_t idx = (size_t)m * N + n;
        if constexpr (EPI == 3) {
          ((float*)C0)[idx] = val + resid[idx];
        }
      }
    }
  }
}

// ---------------- 256x256 4-phase-per-tile GEMM (m201-style schedule, v2)
// (schedule unchanged from round 3; + XCD-bijective block remap)
template <int EPI>
__global__ __launch_bounds__(512, 2) void gemm256(
    const bf16* __restrict__ A, const bf16* __restrict__ Bt,
    const float* __restrict__ bias0, const float* __restrict__ bias1,
    const float* __restrict__ bias2,
    void* __restrict__ C0, void* __restrict__ C1, void* __restrict__ C2,
    int M, int N, int K) {
  __shared__ __align__(16) bf16 As[2][256 * 64];
  __shared__ __align__(16) bf16 Bs[2][256 * 64];
  const int t = threadIdx.x, lane = t & 63, w = t >> 6;
  const int wm = (w >> 2) * 128, wn = (w & 3) * 64;

  const int gx = gridDim.x;
  const int L = blockIdx.y * gx + blockIdx.x;        // hw dispatch order
  const int nwg = gx * gridDim.y;                    // % 8 == 0 at all sites
  const int wg = (L & 7) * (nwg >> 3) + (L >> 3);    // XCD-contiguous
  const int m0 = (wg / gx) * 256, n0 = (wg % gx) * 256;

  const int koff = (EPI == 6) ? (int)blockIdx.z * 1024 : 0;
  const int nk = ((EPI == 6) ? 1024 : K) >> 6;

  const bf16* Abase = A + (size_t)m0 * K + koff;
  const bf16* Bbase = Bt + (size_t)n0 * K + koff;

  const int lrow = lane >> 3;
  const int lgrp = (lane & 7) ^ lrow;
  const size_t lgoff = (size_t)lrow * K + lgrp * 8;

  auto stageA = [&](int buf, int half, int tile) {
    const int r = half * 128 + w * 16;
    const bf16* g = Abase + (size_t)r * K + tile * 64 + lgoff;
    bf16* l = &As[buf][r * 64];
    load16_lds(g, l);
    load16_lds(g + (size_t)8 * K, l + 8 * 64);
  };
  auto stageB = [&](int buf, int half, int tile) {
    const int r = half * 128 + w * 16;
    const bf16* g = Bbase + (size_t)r * K + tile * 64 + lgoff;
    bf16* l = &Bs[buf][r * 64];
    load16_lds(g, l);
    load16_lds(g + (size_t)8 * K, l + 8 * 64);
  };

  const int fr = lane & 15, qd = lane >> 4, frs = fr & 7;
  const int ao0 = (qd ^ frs) * 8;        // kk=0: groups 0..3
  const int ao1 = ((4 + qd) ^ frs) * 8;  // kk=1: groups 4..7
  const int rowA = (wm + fr) * 64;
  const int rowB = (wn + fr) * 64;

  f32x4 acc[8][4] = {};
  bf16x8 aF[8][2], bF[4][2];

#define MFMA_Q(MLO, NLO)                                                   \
  _Pragma("unroll")                                                        \
  for (int mi = (MLO); mi < (MLO) + 4; ++mi)                               \
    _Pragma("unroll")                                                      \
    for (int ni = (NLO); ni < (NLO) + 2; ++ni) {                           \
      acc[mi][ni] = __builtin_amdgcn_mfma_f32_16x16x32_bf16(               \
          aF[mi][0], bF[ni][0], acc[mi][ni], 0, 0, 0);                     \
      acc[mi][ni] = __builtin_amdgcn_mfma_f32_16x16x32_bf16(               \
          aF[mi][1], bF[ni][1], acc[mi][ni], 0, 0, 0);                     \
    }

  stageA(0, 0, 0); stageA(0, 1, 0); stageB(0, 0, 0); stageB(0, 1, 0);
  stageA(1, 0, 1);
  asm volatile("s_waitcnt vmcnt(6)" ::: "memory");
  asm volatile("s_barrier" ::: "memory");

  for (int i = 0; i < nk; ++i) {
    const int c = i & 1;
    const bf16* as = &As[c][0];
    const bf16* bs = &Bs[c][0];

    // ---- Ph_A: read A0 (8); stage Ah1(i+1); fence B(i); Q4(i-1)
    #pragma unroll
    for (int mi = 0; mi < 4; ++mi) {
      aF[mi][0] = *(const bf16x8*)(as + rowA + mi * 1024 + ao0);
      aF[mi][1] = *(const bf16x8*)(as + rowA + mi * 1024 + ao1);
    }
    if (i + 1 < nk) {
      stageA(c ^ 1, 1, i + 1);
      asm volatile("s_waitcnt vmcnt(4)" ::: "memory");
    } else {
      asm volatile("s_waitcnt vmcnt(0)" ::: "memory");
    }
    asm volatile("s_barrier" ::: "memory");
    __builtin_amdgcn_sched_barrier(0);
    if (i) {
      __builtin_amdgcn_s_setprio(1);
      MFMA_Q(4, 2)  // Q4 of tile i-1, register-resident
      __builtin_amdgcn_s_setprio(0);
    }
    __builtin_amdgcn_sched_barrier(0);
    asm volatile("s_barrier" ::: "memory");

    // ---- Ph_B: read B0 (4); stage Bh0(i+1); Q1 = A0 x B0
    #pragma unroll
    for (int ni = 0; ni < 2; ++ni) {
      bF[ni][0] = *(const bf16x8*)(bs + rowB + ni * 1024 + ao0);
      bF[ni][1] = *(const bf16x8*)(bs + rowB + ni * 1024 + ao1);
    }
    if (i + 1 < nk) stageB(c ^ 1, 0, i + 1);
    asm volatile("s_barrier" ::: "memory");
    asm volatile("s_waitcnt lgkmcnt(0)" ::: "memory");
    __builtin_amdgcn_sched_barrier(0);
    __builtin_amdgcn_s_setprio(1);
    MFMA_Q(0, 0)
    __builtin_amdgcn_s_setprio(0);
    __builtin_amdgcn_sched_barrier(0);
    asm volatile("s_barrier" ::: "memory");

    // ---- Ph_C: read A1 (8); stage Bh1(i+1); Q2 = A1 x B0
    #pragma unroll
    for (int mi = 4; mi < 8; ++mi) {
      aF[mi][0] = *(const bf16x8*)(as + rowA + mi * 1024 + ao0);
      aF[mi][1] = *(const bf16x8*)(as + rowA + mi * 1024 + ao1);
    }
    if (i + 1 < nk) stageB(c ^ 1, 1, i + 1);
    asm volatile("s_barrier" ::: "memory");
    asm volatile("s_waitcnt lgkmcnt(0)" ::: "memory");
    __builtin_amdgcn_sched_barrier(0);
    __builtin_amdgcn_s_setprio(1);
    MFMA_Q(4, 0)
    __builtin_amdgcn_s_setprio(0);
    __builtin_amdgcn_sched_barrier(0);
    asm volatile("s_barrier" ::: "memory");

    // ---- Ph_D: read B1 (4); stage Ah0(i+2); fence A(i+1); Q3 = A0 x B1
    #pragma unroll
    for (int ni = 2; ni < 4; ++ni) {
      bF[ni][0] = *(const bf16x8*)(bs + rowB + ni * 1024 + ao0);
      bF[ni][1] = *(const bf16x8*)(bs + rowB + ni * 1024 + ao1);
    }
    if (i + 2 < nk) stageA(c, 0, i + 2);
    if (i + 1 < nk) {
      if (i + 2 < nk) {
        asm volatile("s_waitcnt vmcnt(6)" ::: "memory");
      } else {
        asm volatile("s_waitcnt vmcnt(4)" ::: "memory");
      }
    }
    asm volatile("s_barrier" ::: "memory");
    asm volatile("s_waitcnt lgkmcnt(0)" ::: "memory");
    __builtin_amdgcn_sched_barrier(0);
    __builtin_amdgcn_s_setprio(1);
    MFMA_Q(0, 2)
    __builtin_amdgcn_s_setprio(0);
    __builtin_amdgcn_sched_barrier(0);
    asm volatile("s_barrier" ::: "memory");
  }
  MFMA_Q(4, 2)
#undef MFMA_Q

  if constexpr (EPI == 0) {
    const int which = n0 >> 10;  // block-uniform (1024 % 256 == 0)
    const float* bp = which == 0 ? bias0 : which == 1 ? bias1 : bias2;
    bf16* qk = (bf16*)(which == 0 ? C0 : C1);
    const float qscale = 0.18033688011112042f;  // 0.125 * log2(e)
    #pragma unroll
    for (int mi = 0; mi < 8; ++mi) {
      #pragma unroll
      for (int reg = 0; reg < 4; ++reg) {
        int m = m0 + wm + mi * 16 + qd * 4 + reg;
        int b = m >> 11, tok = m & 2047;
        #pragma unroll
        for (int ni = 0; ni < 4; ++ni) {
          int n = n0 + wn + ni * 16 + fr;
          int nn = n & 1023, hh = nn >> 6, d = n & 63;
          float val = acc[mi][ni][reg] + bp[nn];
          if (which == 2)
            ((bf16*)C2)[(size_t)((b * 16 + hh) * 64 + d) * 2048 + tok] =
                __float2bfloat16(val);
          else if (which == 0)
            qk[(size_t)((b * 16 + hh) * 2048 + tok) * 64 + d] =
                __float2bfloat16(val * qscale);
          else
            qk[(size_t)((b * 16 + hh) * 2048 + tok) * 64 + d] =
                __float2bfloat16(val);
        }
      }
    }
  } else if constexpr (EPI == 4) {
    #pragma unroll
    for (int mi = 0; mi < 8; ++mi) {
      #pragma unroll
      for (int reg = 0; reg < 4; ++reg) {
        int m = m0 + wm + mi * 16 + qd * 4 + reg;
        #pragma unroll
        for (int ni = 0; ni < 4; ++ni) {
          int n = n0 + wn + ni * 16 + fr;
          float val = acc[mi][ni][reg] + bias0[n];
          ((bf16*)C0)[(size_t)m * N + n] = __float2bfloat16(gelu_f(val));
        }
      }
    }
  } else {  // EPI == 6
    bf16* pout = (bf16*)C0 + (size_t)blockIdx.z * M * N;
    #pragma unroll
    for (int mi = 0; mi < 8; ++mi) {
      #pragma unroll
      for (int reg = 0; reg < 4; ++reg) {
        int m = m0 + wm + mi * 16 + qd * 4 + reg;
        #pragma unroll
        for (int ni = 0; ni < 4; ++ni) {
          int n = n0 + wn + ni * 16 + fr;
          pout[(size_t)m * N + n] = __float2bfloat16(acc[mi][ni][reg]);
        }
      }
    }
  }
}

// ---------------- split-K reduce for MLP2: out = gelu(sum partials + b2) + out1
__global__ __launch_bounds__(256) void reduce_mlp2(
    const bf16* __restrict__ part, const float* __restrict__ b2,
    const float* __restrict__ out1, float* __restrict__ out) {
  const int row = blockIdx.x, t = threadIdx.x;
  const size_t base = (size_t)row * 1024 + t * 4;
  float sum[4] = {0.f, 0.f, 0.f, 0.f};
  #pragma unroll
  for (int kc = 0; kc < 4; ++kc) {
    ushort4 u = *(const ushort4*)(part + (size_t)kc * 4096 * 1024 + base);
    unsigned short us[4] = {u.x, u.y, u.z, u.w};
    #pragma unroll
    for (int j = 0; j < 4; ++j) {
      bf16 h;
      __builtin_memcpy(&h, &us[j], 2);
      sum[j] += __bfloat162float(h);
    }
  }
  float4 bv = ((const float4*)b2)[t];
  float4 rv = *(const float4*)(out1 + base);
  float4 o;
  o.x = gelu_f(sum[0] + bv.x) + rv.x;
  o.y = gelu_f(sum[1] + bv.y) + rv.y;
  o.z = gelu_f(sum[2] + bv.z) + rv.z;
  o.w = gelu_f(sum[3] + bv.w) + rv.w;
  *(float4*)(out + base) = o;
}

// ---------------- Flash attention, off-by-one softmax + head slimming
// q is PRESCALED by C=0.125*log2(e), so p = exp2(q.k) directly.
// S^T trick + QBLK=128 + XOR-swizzled K/V LDS + XCD remap (round 8/9).
// v10: T12 — P stays IN REGISTERS. Lane (fr,qd) holds P[fr][nc*16+qd*4+r];
// PV needs pf0 = P[fr][qd*8..+7], pf1 = P[fr][32+qd*8..+7]. Packing pairs
// into u32 W[nc][h] (keys nc*16+qd*4+{2h,2h+1}), the needed permutation is
// a perfect shuffle of (W0,W1)->pf0 and (W2,W3)->pf1:
//   permlane32_swap(A,B): newA=[A0,A1,B0,B1], newB=[A2,A3,B2,B3]  (qd rows)
//   permlane16_swap(P,Q): newP=[P0,Q0,P2,Q2], newQ=[P1,Q1,P3,Q3]
//   -> X=[a0,a2,b0,b2] (src lane 2(qd&1)),  Y=[a1,a3,b1,b3] (src 2(qd&1)+1)
//   pf0 = [X_h0, X_h1, Y_h0, Y_h1]; pf1 likewise from (W2,W3).
// Removes 8 ds_write_b64 + 4 ds_read_b128 + both lgkm P round-trips per
// iter; Ps LDS (16 KB) deleted. Falls back to round-9 Ps path if the
// permlane builtins are unavailable.
__global__ __launch_bounds__(256) void attn_kernel(
    const bf16* __restrict__ q, const bf16* __restrict__ k,
    const bf16* __restrict__ vt, const float* __restrict__ slim,
    bf16* __restrict__ attn) {
  __shared__ __align__(16) bf16 Ks[64][64];
  __shared__ __align__(16) bf16 Vs[64][64];
#if !HAVE_PERMLANE_SWAP
  __shared__ __align__(16) bf16 Ps[4][2][16][64];
#endif

  const int t = threadIdx.x, lane = t & 63, w = t >> 6;
  const int fr = lane & 15, qd = lane >> 4;

  const int L = blockIdx.y * 16 + blockIdx.x;   // hw dispatch order (512 wgs)
  const int wg = (L & 7) * 64 + (L >> 3);       // XCD k -> contiguous 64 wgs
  const int bh = wg >> 4;                       // 4 heads per XCD chunk
  const int q0 = (wg & 15) * 128;

  const size_t bhbase = (size_t)bh * 2048 * 64;

  bf16x8 qf[2][2];
  #pragma unroll
  for (int s = 0; s < 2; ++s) {
    const int qrow = q0 + s * 64 + w * 16 + fr;
    const bf16* qp = q + bhbase + (size_t)qrow * 64 + qd * 8;
    qf[s][0] = *(const bf16x8*)qp;
    qf[s][1] = *(const bf16x8*)(qp + 32);
  }

  const int r0 = t >> 3, g0 = t & 7;
  const bf16* kbase = k + bhbase + (size_t)r0 * 64 + g0 * 8;
  const bf16* vbase = vt + bhbase + (size_t)r0 * 2048 + g0 * 8;

  // swizzled LDS write slot: (r0+32)&7 == r0&7, so one value serves both rows
  const int wsw = (g0 ^ (r0 & 7)) * 8;

  bf16x8 kreg0, kreg1, vreg0, vreg1;
  auto gload = [&](int j0) {
    kreg0 = *(const bf16x8*)(kbase + (size_t)j0 * 64);
    kreg1 = *(const bf16x8*)(kbase + (size_t)(j0 + 32) * 64);
    vreg0 = *(const bf16x8*)(vbase + j0);
    vreg1 = *(const bf16x8*)(vbase + (size_t)32 * 2048 + j0);
  };
  gload(0);

  f32x4 o_acc[2][4] = {};
  float m4[2][4] = {};
  float l4[2][4] = {};

  const int frs = fr & 7;
  const int so0 = (qd ^ frs) * 8;        // half 0: groups 0..3
  const int so1 = ((4 + qd) ^ frs) * 8;  // half 1: groups 4..7

  for (int it = 0; it < 32; ++it) {
    *(bf16x8*)&Ks[r0][wsw] = kreg0;
    *(bf16x8*)&Ks[r0 + 32][wsw] = kreg1;
    *(bf16x8*)&Vs[r0][wsw] = vreg0;
    *(bf16x8*)&Vs[r0 + 32][wsw] = vreg1;
    __syncthreads();
    if (it + 1 < 32) gload((it + 1) * 64);

    bf16x8 kf[4][2];
    #pragma unroll
    for (int nc = 0; nc < 4; ++nc) {
      const bf16* kr = &Ks[nc * 16 + fr][0];
      kf[nc][0] = *(const bf16x8*)(kr + so0);
      kf[nc][1] = *(const bf16x8*)(kr + so1);
    }

    f32x4 z[2][4];
    #pragma unroll
    for (int s = 0; s < 2; ++s)
      #pragma unroll
      for (int nc = 0; nc < 4; ++nc) {
        f32x4 zz = {};
        zz = __builtin_amdgcn_mfma_f32_16x16x32_bf16(kf[nc][0], qf[s][0], zz, 0, 0, 0);
        zz = __builtin_amdgcn_mfma_f32_16x16x32_bf16(kf[nc][1], qf[s][1], zz, 0, 0, 0);
        z[s][nc] = zz;
      }

    bf16x8 vf[4][2];
    #pragma unroll
    for (int dc = 0; dc < 4; ++dc) {
      const bf16* vr = &Vs[dc * 16 + fr][0];
      vf[dc][0] = *(const bf16x8*)(vr + so0);
      vf[dc][1] = *(const bf16x8*)(vr + so1);
    }

    #pragma unroll
    for (int s = 0; s < 2; ++s) {
      unsigned Wv[4][2];
      #pragma unroll
      for (int nc = 0; nc < 4; ++nc) {
        float p0 = __builtin_amdgcn_exp2f(z[s][nc][0]);
        float p1 = __builtin_amdgcn_exp2f(z[s][nc][1]);
        float p2 = __builtin_amdgcn_exp2f(z[s][nc][2]);
        float p3 = __builtin_amdgcn_exp2f(z[s][nc][3]);
        l4[s][nc] += (p0 + p1) + (p2 + p3);
        m4[s][nc] = fmaxf(m4[s][nc], fmaxf(fmaxf(p0, p1), fmaxf(p2, p3)));
        Wv[nc][0] = (unsigned)f2bfu(p0) | ((unsigned)f2bfu(p1) << 16);
        Wv[nc][1] = (unsigned)f2bfu(p2) | ((unsigned)f2bfu(p3) << 16);
      }

      bf16x8 pf0, pf1;
#if HAVE_PERMLANE_SWAP
      u32x4 pw0, pw1;
      #pragma unroll
      for (int h = 0; h < 2; ++h) {
        u32x2 ab = __builtin_amdgcn_permlane32_swap(Wv[0][h], Wv[1][h],
                                                    false, false);
        u32x2 xy = __builtin_amdgcn_permlane16_swap(ab[0], ab[1],
                                                    false, false);
        pw0[h] = xy[0];
        pw0[2 + h] = xy[1];
        u32x2 cd = __builtin_amdgcn_permlane32_swap(Wv[2][h], Wv[3][h],
                                                    false, false);
        u32x2 uv = __builtin_amdgcn_permlane16_swap(cd[0], cd[1],
                                                    false, false);
        pw1[h] = uv[0];
        pw1[2 + h] = uv[1];
      }
      pf0 = *(const bf16x8*)&pw0;
      pf1 = *(const bf16x8*)&pw1;
#else
      #pragma unroll
      for (int nc = 0; nc < 4; ++nc) {
        const int pcol = (((2 * nc + (qd >> 1)) ^ frs) << 3) + ((qd & 1) << 2);
        *(unsigned*)&Ps[w][s][fr][pcol] = Wv[nc][0];
        *(unsigned*)&Ps[w][s][fr][pcol + 2] = Wv[nc][1];
      }
      pf0 = *(const bf16x8*)&Ps[w][s][fr][so0];
      pf1 = *(const bf16x8*)&Ps[w][s][fr][so1];
#endif
      #pragma unroll
      for (int dc = 0; dc < 4; ++dc) {
        o_acc[s][dc] = __builtin_amdgcn_mfma_f32_16x16x32_bf16(pf0, vf[dc][0], o_acc[s][dc], 0, 0, 0);
        o_acc[s][dc] = __builtin_amdgcn_mfma_f32_16x16x32_bf16(pf1, vf[dc][1], o_acc[s][dc], 0, 0, 0);
      }
    }
    __syncthreads();
  }

  const int b = bh >> 4, hh = bh & 15;
  const float sl_f = slim[hh];
  #pragma unroll
  for (int s = 0; s < 2; ++s) {
    float l_all = (l4[s][0] + l4[s][1]) + (l4[s][2] + l4[s][3]);
    float m_all = fmaxf(fmaxf(m4[s][0], m4[s][1]), fmaxf(m4[s][2], m4[s][3]));
    l_all += __shfl_xor(l_all, 16);
    m_all = fmaxf(m_all, __shfl_xor(m_all, 16));
    l_all += __shfl_xor(l_all, 32);
    m_all = fmaxf(m_all, __shfl_xor(m_all, 32));

    #pragma unroll
    for (int r = 0; r < 4; ++r) {
      float lr = __shfl(l_all, qd * 4 + r);
      float mr = __shfl(m_all, qd * 4 + r);
      float inv = sl_f / (mr + lr);
      int mrow = b * 2048 + q0 + s * 64 + w * 16 + qd * 4 + r;
      #pragma unroll
      for (int dc = 0; dc < 4; ++dc) {
        int col = hh * 64 + dc * 16 + fr;
        attn[(size_t)mrow * 1024 + col] = __float2bfloat16(o_acc[s][dc][r] * inv);
      }
    }
  }
}

extern "C" void kernel_launch(void* const* d_in, const int* in_sizes, int n_in,
                              void* d_out, int out_size, void* d_ws, size_t ws_size,
                              hipStream_t stream) {
  const float* x    = (const float*)d_in[0];
  const float* ln1g = (const float*)d_in[1];
  const float* ln1b = (const float*)d_in[2];
  const float* Wq   = (const float*)d_in[3];
  const float* bq   = (const float*)d_in[4];
  const float* Wk   = (const float*)d_in[5];
  const float* bk   = (const float*)d_in[6];
  const float* Wv   = (const float*)d_in[7];
  const float* bv   = (const float*)d_in[8];
  const float* Wo   = (const float*)d_in[9];
  const float* bo   = (const float*)d_in[10];
  const float* slim = (const float*)d_in[11];
  const float* ln2g = (const float*)d_in[12];
  const float* ln2b = (const float*)d_in[13];
  const float* W1   = (const float*)d_in[14];
  const float* b1   = (const float*)d_in[15];
  const float* W2   = (const float*)d_in[16];
  const float* b2   = (const float*)d_in[17];

  char* p = (char*)d_ws;
  auto take = [&](size_t nbytes) {
    char* r = p;
    p += (nbytes + 255) & ~(size_t)255;
    return r;
  };
  bf16* Wqkv_t = (bf16*)take((size_t)3072 * 1024 * 2);
  bf16* Wo_t = (bf16*)take((size_t)1024 * 1024 * 2);
  bf16* W1_t = (bf16*)take((size_t)4096 * 1024 * 2);
  bf16* W2_t = (bf16*)take((size_t)1024 * 4096 * 2);
  bf16* h1   = (bf16*)take((size_t)4096 * 1024 * 2);   // also partial[0]
  bf16* qb   = (bf16*)take((size_t)4096 * 1024 * 2);   // also partial[1]
  bf16* kb   = (bf16*)take((size_t)4096 * 1024 * 2);   // also partial[2]
  bf16* vtb  = (bf16*)take((size_t)4096 * 1024 * 2);   // also partial[3]
  bf16* attn = (bf16*)take((size_t)4096 * 1024 * 2);
  float* out1 = (float*)take((size_t)4096 * 1024 * 4);
  bf16* h2   = (bf16*)take((size_t)4096 * 1024 * 2);
  bf16* m1   = (bf16*)take((size_t)4096 * 4096 * 2);

  bf16* parts = h1;

  dim3 blk(256);
  dim3 blk512(512);

  // 4 square weight transposes in one launch (z = Wq,Wk,Wv,Wo)
  transpose_cast_qkvo<<<dim3(32, 32, 4), blk, 0, stream>>>(
      Wq, Wk, Wv, Wo, Wqkv_t, Wo_t);
  transpose_cast<<<dim3(128, 32), blk, 0, stream>>>(W1, W1_t, 1024, 4096);
  transpose_cast<<<dim3(32, 128), blk, 0, stream>>>(W2, W2_t, 4096, 1024);

  ln_kernel<<<4096, blk, 0, stream>>>(x, ln1g, ln1b, h1);

  // fused QKV: N = 3072 (q output prescaled by 0.125*log2e), 256² 4-phase
  gemm256<0><<<dim3(12, 16), blk512, 0, stream>>>(
      h1, Wqkv_t, bq, bk, bv, qb, kb, vtb, 4096, 3072, 1024);

  attn_kernel<<<dim3(16, 32), blk, 0, stream>>>(qb, kb, vtb, slim, attn);

  gemm_bf16<3><<<dim3(8, 32), blk, 0, stream>>>(
      attn, Wo_t, bo, x, out1, 4096, 1024, 1024);

  ln_kernel<<<4096, blk, 0, stream>>>(out1, ln2g, ln2b, h2);

  // MLP1: 256² 4-phase, 256 blocks = 1/CU
  gemm256<4><<<dim3(16, 16), blk512, 0, stream>>>(
      h2, W1_t, b1, nullptr, nullptr, m1, nullptr, nullptr, 4096, 4096, 1024);

  // MLP2 split-K=4: 256² 4-phase, 64 blocks x 4 K-chunks
  gemm256<6><<<dim3(4, 16, 4), blk512, 0, stream>>>(
      m1, W2_t, nullptr, nullptr, nullptr, parts, nullptr, nullptr,
      4096, 1024, 4096);
  reduce_mlp2<<<4096, blk, 0, stream>>>(parts, b2, out1, (float*)d_out);
}

// Round 11
// 393.087 us; speedup vs baseline: 1.0086x; 1.0086x over previous
//
#include <hip/hip_runtime.h>
#include <hip/hip_bf16.h>

typedef __hip_bfloat16 bf16;
typedef short bf16x8 __attribute__((ext_vector_type(8)));
typedef short bf16x4 __attribute__((ext_vector_type(4)));
typedef float f32x4 __attribute__((ext_vector_type(4)));

__device__ __forceinline__ float gelu_f(float x) {
  return 0.5f * x * (1.f + erff(x * 0.70710678118654752f));
}

__device__ __forceinline__ unsigned short f2bfu(float f) {
  bf16 h = __float2bfloat16(f);
  unsigned short u;
  __builtin_memcpy(&u, &h, 2);
  return u;
}

// async 16B/lane global->LDS; lds dest is wave-uniform base + lane*16
__device__ __forceinline__ void load16_lds(const bf16* g, bf16* l) {
  __builtin_amdgcn_global_load_lds(
      (const __attribute__((address_space(1))) unsigned int*)g,
      (__attribute__((address_space(3))) unsigned int*)l, 16, 0, 0);
}

// batched 1024x1024 transpose for Wq/Wk/Wv/Wo in ONE launch (z = 0..3)
__global__ __launch_bounds__(256) void transpose_cast_qkvo(
    const float* __restrict__ s0, const float* __restrict__ s1,
    const float* __restrict__ s2, const float* __restrict__ s3,
    bf16* __restrict__ dqkv, bf16* __restrict__ dwo) {
  __shared__ float tile[32][33];
  const int z = blockIdx.z;
  const float* src = z == 0 ? s0 : z == 1 ? s1 : z == 2 ? s2 : s3;
  bf16* dst = z < 3 ? dqkv + (size_t)z * 1024 * 1024 : dwo;
  int tx = threadIdx.x & 31, ty = threadIdx.x >> 5;  // 32 x 8
  int r0 = blockIdx.y * 32, c0 = blockIdx.x * 32;
  #pragma unroll
  for (int i = ty; i < 32; i += 8)
    tile[i][tx] = src[(size_t)(r0 + i) * 1024 + (c0 + tx)];
  __syncthreads();
  #pragma unroll
  for (int i = ty; i < 32; i += 8)
    dst[(size_t)(c0 + i) * 1024 + (r0 + tx)] = __float2bfloat16(tile[tx][i]);
}

// batched rectangular transposes: z=0 W1 (1024x4096), z=1 W2 (4096x1024),
// one 4096-block launch each (uniform grid, per-z block-coord decode)
__global__ __launch_bounds__(256) void transpose_cast_w12(
    const float* __restrict__ w1, const float* __restrict__ w2,
    bf16* __restrict__ d1, bf16* __restrict__ d2) {
  __shared__ float tile[32][33];
  const int z = blockIdx.z;
  const float* src = z == 0 ? w1 : w2;
  bf16* dst = z == 0 ? d1 : d2;
  const int R = z == 0 ? 1024 : 4096;
  const int C = z == 0 ? 4096 : 1024;
  const int bx = blockIdx.x;
  const int ctiles = C >> 5;
  int c0 = (bx % ctiles) * 32, r0 = (bx / ctiles) * 32;
  int tx = threadIdx.x & 31, ty = threadIdx.x >> 5;  // 32 x 8
  #pragma unroll
  for (int i = ty; i < 32; i += 8)
    tile[i][tx] = src[(size_t)(r0 + i) * C + (c0 + tx)];
  __syncthreads();
  #pragma unroll
  for (int i = ty; i < 32; i += 8)
    dst[(size_t)(c0 + i) * R + (r0 + tx)] = __float2bfloat16(tile[tx][i]);
}

// ---------------- LayerNorm: x fp32 [rows][1024] -> y bf16, one block per row
__global__ __launch_bounds__(256) void ln_kernel(
    const float* __restrict__ x, const float* __restrict__ g,
    const float* __restrict__ b, bf16* __restrict__ y) {
  int row = blockIdx.x;
  int t = threadIdx.x;
  const float4* xr = (const float4*)(x + (size_t)row * 1024);
  float4 v = xr[t];
  float s = v.x + v.y + v.z + v.w;
  float ss = v.x * v.x + v.y * v.y + v.z * v.z + v.w * v.w;
  #pragma unroll
  for (int off = 32; off >= 1; off >>= 1) {
    s += __shfl_xor(s, off);
    ss += __shfl_xor(ss, off);
  }
  __shared__ float red[8];
  int wv = t >> 6;
  if ((t & 63) == 0) { red[wv] = s; red[4 + wv] = ss; }
  __syncthreads();
  float S = red[0] + red[1] + red[2] + red[3];
  float SS = red[4] + red[5] + red[6] + red[7];
  float mu = S * (1.f / 1024.f);
  float var = SS * (1.f / 1024.f) - mu * mu;
  float inv = rsqrtf(var + 1e-5f);
  float4 gv = ((const float4*)g)[t];
  float4 bv = ((const float4*)b)[t];
  ushort4 o;
  o.x = f2bfu((v.x - mu) * inv * gv.x + bv.x);
  o.y = f2bfu((v.y - mu) * inv * gv.y + bv.y);
  o.z = f2bfu((v.z - mu) * inv * gv.z + bv.z);
  o.w = f2bfu((v.w - mu) * inv * gv.w + bv.w);
  ((ushort4*)(y + (size_t)row * 1024))[t] = o;
}

// ---------------- 128x128 GEMM (m97 structure) — kept for the Wo projection
// EPI 3: fp32 out = val + resid
// XCD-bijective block remap (grid.x*grid.y % 8 == 0 at all call sites).
template <int EPI>
__global__ __launch_bounds__(256) void gemm_bf16(
    const bf16* __restrict__ A, const bf16* __restrict__ Bt,
    const float* __restrict__ bias0, const float* __restrict__ resid,
    void* __restrict__ C0, int M, int N, int K) {
  __shared__ __align__(16) bf16 As[2][128 * 32];
  __shared__ __align__(16) bf16 Bs[2][128 * 32];
  const int t = threadIdx.x, lane = t & 63, w = t >> 6;
  const int wm = (w >> 1) * 64, wn = (w & 1) * 64;

  const int gx = gridDim.x;
  const int L = blockIdx.y * gx + blockIdx.x;        // hw dispatch order
  const int nwg = gx * gridDim.y;
  const int wg = (L & 7) * (nwg >> 3) + (L >> 3);    // XCD-contiguous
  const int m0 = (wg / gx) * 128, n0 = (wg % gx) * 128;

  const int srow = lane >> 2;
  const int sgrp = lane & 3;
  f32x4 acc[4][4] = {};

  const bf16* Abase = A + (size_t)m0 * K;
  const bf16* Bbase = Bt + (size_t)n0 * K;

  auto stage = [&](int buf, int kt) {
    #pragma unroll
    for (int c = 0; c < 2; ++c) {
      int row = w * 32 + c * 16 + srow;
      int sw = (row & 3) ^ ((row >> 2) & 3);
      int gg = sgrp ^ sw;
      const bf16* ga = Abase + (size_t)row * K + kt + gg * 8;
      const bf16* gb = Bbase + (size_t)row * K + kt + gg * 8;
      load16_lds(ga, &As[buf][(w * 32 + c * 16) * 32]);
      load16_lds(gb, &Bs[buf][(w * 32 + c * 16) * 32]);
    }
  };

  const int q8 = (((lane >> 4) ^ (lane & 3) ^ ((lane >> 2) & 3))) * 8;
  const int fr = lane & 15;

  const int nk = K >> 5;
  stage(0, 0);
  for (int i = 0; i < nk; ++i) {
    const int cur = i & 1;
    __syncthreads();
    if (i + 1 < nk) stage(cur ^ 1, (i + 1) << 5);
    bf16x8 af[4], bfr[4];
    #pragma unroll
    for (int mc = 0; mc < 4; ++mc)
      af[mc] = *(const bf16x8*)&As[cur][(wm + mc * 16 + fr) * 32 + q8];
    #pragma unroll
    for (int nc = 0; nc < 4; ++nc)
      bfr[nc] = *(const bf16x8*)&Bs[cur][(wn + nc * 16 + fr) * 32 + q8];
    #pragma unroll
    for (int mc = 0; mc < 4; ++mc)
      #pragma unroll
      for (int nc = 0; nc < 4; ++nc)
        acc[mc][nc] = __builtin_amdgcn_mfma_f32_16x16x32_bf16(
            af[mc], bfr[nc], acc[mc][nc], 0, 0, 0);
  }

  #pragma unroll
  for (int mc = 0; mc < 4; ++mc) {
    #pragma unroll
    for (int reg = 0; reg < 4; ++reg) {
      int m = m0 + wm + mc * 16 + ((lane >> 4) << 2) + reg;
      #pragma unroll
      for (int nc = 0; nc < 4; ++nc) {
        int n = n0 + wn + nc * 16 + (lane & 15);
        float val = acc[mc][nc][reg] + bias0[n];
        size_t idx = (size_t)m * N + n;
        if constexpr (EPI == 3) {
          ((float*)C0)[idx] = val + resid[idx];
        }
      }
    }
  }
}

// ---------------- 256x256 4-phase-per-tile GEMM (m201-style schedule, v2)
// (schedule unchanged from round 3; + XCD-bijective block remap)
template <int EPI>
__global__ __launch_bounds__(512, 2) void gemm256(
    const bf16* __restrict__ A, const bf16* __restrict__ Bt,
    const float* __restrict__ bias0, const float* __restrict__ bias1,
    const float* __restrict__ bias2,
    void* __restrict__ C0, void* __restrict__ C1, void* __restrict__ C2,
    int M, int N, int K) {
  __shared__ __align__(16) bf16 As[2][256 * 64];
  __shared__ __align__(16) bf16 Bs[2][256 * 64];
  const int t = threadIdx.x, lane = t & 63, w = t >> 6;
  const int wm = (w >> 2) * 128, wn = (w & 3) * 64;

  const int gx = gridDim.x;
  const int L = blockIdx.y * gx + blockIdx.x;        // hw dispatch order
  const int nwg = gx * gridDim.y;                    // % 8 == 0 at all sites
  const int wg = (L & 7) * (nwg >> 3) + (L >> 3);    // XCD-contiguous
  const int m0 = (wg / gx) * 256, n0 = (wg % gx) * 256;

  const int koff = (EPI == 6) ? (int)blockIdx.z * 1024 : 0;
  const int nk = ((EPI == 6) ? 1024 : K) >> 6;

  const bf16* Abase = A + (size_t)m0 * K + koff;
  const bf16* Bbase = Bt + (size_t)n0 * K + koff;

  const int lrow = lane >> 3;
  const int lgrp = (lane & 7) ^ lrow;
  const size_t lgoff = (size_t)lrow * K + lgrp * 8;

  auto stageA = [&](int buf, int half, int tile) {
    const int r = half * 128 + w * 16;
    const bf16* g = Abase + (size_t)r * K + tile * 64 + lgoff;
    bf16* l = &As[buf][r * 64];
    load16_lds(g, l);
    load16_lds(g + (size_t)8 * K, l + 8 * 64);
  };
  auto stageB = [&](int buf, int half, int tile) {
    const int r = half * 128 + w * 16;
    const bf16* g = Bbase + (size_t)r * K + tile * 64 + lgoff;
    bf16* l = &Bs[buf][r * 64];
    load16_lds(g, l);
    load16_lds(g + (size_t)8 * K, l + 8 * 64);
  };

  const int fr = lane & 15, qd = lane >> 4, frs = fr & 7;
  const int ao0 = (qd ^ frs) * 8;        // kk=0: groups 0..3
  const int ao1 = ((4 + qd) ^ frs) * 8;  // kk=1: groups 4..7
  const int rowA = (wm + fr) * 64;
  const int rowB = (wn + fr) * 64;

  f32x4 acc[8][4] = {};
  bf16x8 aF[8][2], bF[4][2];

#define MFMA_Q(MLO, NLO)                                                   \
  _Pragma("unroll")                                                        \
  for (int mi = (MLO); mi < (MLO) + 4; ++mi)                               \
    _Pragma("unroll")                                                      \
    for (int ni = (NLO); ni < (NLO) + 2; ++ni) {                           \
      acc[mi][ni] = __builtin_amdgcn_mfma_f32_16x16x32_bf16(               \
          aF[mi][0], bF[ni][0], acc[mi][ni], 0, 0, 0);                     \
      acc[mi][ni] = __builtin_amdgcn_mfma_f32_16x16x32_bf16(               \
          aF[mi][1], bF[ni][1], acc[mi][ni], 0, 0, 0);                     \
    }

  stageA(0, 0, 0); stageA(0, 1, 0); stageB(0, 0, 0); stageB(0, 1, 0);
  stageA(1, 0, 1);
  asm volatile("s_waitcnt vmcnt(6)" ::: "memory");
  asm volatile("s_barrier" ::: "memory");

  for (int i = 0; i < nk; ++i) {
    const int c = i & 1;
    const bf16* as = &As[c][0];
    const bf16* bs = &Bs[c][0];

    // ---- Ph_A: read A0 (8); stage Ah1(i+1); fence B(i); Q4(i-1)
    #pragma unroll
    for (int mi = 0; mi < 4; ++mi) {
      aF[mi][0] = *(const bf16x8*)(as + rowA + mi * 1024 + ao0);
      aF[mi][1] = *(const bf16x8*)(as + rowA + mi * 1024 + ao1);
    }
    if (i + 1 < nk) {
      stageA(c ^ 1, 1, i + 1);
      asm volatile("s_waitcnt vmcnt(4)" ::: "memory");
    } else {
      asm volatile("s_waitcnt vmcnt(0)" ::: "memory");
    }
    asm volatile("s_barrier" ::: "memory");
    __builtin_amdgcn_sched_barrier(0);
    if (i) {
      __builtin_amdgcn_s_setprio(1);
      MFMA_Q(4, 2)  // Q4 of tile i-1, register-resident
      __builtin_amdgcn_s_setprio(0);
    }
    __builtin_amdgcn_sched_barrier(0);
    asm volatile("s_barrier" ::: "memory");

    // ---- Ph_B: read B0 (4); stage Bh0(i+1); Q1 = A0 x B0
    #pragma unroll
    for (int ni = 0; ni < 2; ++ni) {
      bF[ni][0] = *(const bf16x8*)(bs + rowB + ni * 1024 + ao0);
      bF[ni][1] = *(const bf16x8*)(bs + rowB + ni * 1024 + ao1);
    }
    if (i + 1 < nk) stageB(c ^ 1, 0, i + 1);
    asm volatile("s_barrier" ::: "memory");
    asm volatile("s_waitcnt lgkmcnt(0)" ::: "memory");
    __builtin_amdgcn_sched_barrier(0);
    __builtin_amdgcn_s_setprio(1);
    MFMA_Q(0, 0)
    __builtin_amdgcn_s_setprio(0);
    __builtin_amdgcn_sched_barrier(0);
    asm volatile("s_barrier" ::: "memory");

    // ---- Ph_C: read A1 (8); stage Bh1(i+1); Q2 = A1 x B0
    #pragma unroll
    for (int mi = 4; mi < 8; ++mi) {
      aF[mi][0] = *(const bf16x8*)(as + rowA + mi * 1024 + ao0);
      aF[mi][1] = *(const bf16x8*)(as + rowA + mi * 1024 + ao1);
    }
    if (i + 1 < nk) stageB(c ^ 1, 1, i + 1);
    asm volatile("s_barrier" ::: "memory");
    asm volatile("s_waitcnt lgkmcnt(0)" ::: "memory");
    __builtin_amdgcn_sched_barrier(0);
    __builtin_amdgcn_s_setprio(1);
    MFMA_Q(4, 0)
    __builtin_amdgcn_s_setprio(0);
    __builtin_amdgcn_sched_barrier(0);
    asm volatile("s_barrier" ::: "memory");

    // ---- Ph_D: read B1 (4); stage Ah0(i+2); fence A(i+1); Q3 = A0 x B1
    #pragma unroll
    for (int ni = 2; ni < 4; ++ni) {
      bF[ni][0] = *(const bf16x8*)(bs + rowB + ni * 1024 + ao0);
      bF[ni][1] = *(const bf16x8*)(bs + rowB + ni * 1024 + ao1);
    }
    if (i + 2 < nk) stageA(c, 0, i + 2);
    if (i + 1 < nk) {
      if (i + 2 < nk) {
        asm volatile("s_waitcnt vmcnt(6)" ::: "memory");
      } else {
        asm volatile("s_waitcnt vmcnt(4)" ::: "memory");
      }
    }
    asm volatile("s_barrier" ::: "memory");
    asm volatile("s_waitcnt lgkmcnt(0)" ::: "memory");
    __builtin_amdgcn_sched_barrier(0);
    __builtin_amdgcn_s_setprio(1);
    MFMA_Q(0, 2)
    __builtin_amdgcn_s_setprio(0);
    __builtin_amdgcn_sched_barrier(0);
    asm volatile("s_barrier" ::: "memory");
  }
  MFMA_Q(4, 2)
#undef MFMA_Q

  if constexpr (EPI == 0) {
    const int which = n0 >> 10;  // block-uniform (1024 % 256 == 0)
    const float* bp = which == 0 ? bias0 : which == 1 ? bias1 : bias2;
    bf16* qk = (bf16*)(which == 0 ? C0 : C1);
    const float qscale = 0.18033688011112042f;  // 0.125 * log2(e)
    #pragma unroll
    for (int mi = 0; mi < 8; ++mi) {
      #pragma unroll
      for (int reg = 0; reg < 4; ++reg) {
        int m = m0 + wm + mi * 16 + qd * 4 + reg;
        int b = m >> 11, tok = m & 2047;
        #pragma unroll
        for (int ni = 0; ni < 4; ++ni) {
          int n = n0 + wn + ni * 16 + fr;
          int nn = n & 1023, hh = nn >> 6, d = n & 63;
          float val = acc[mi][ni][reg] + bp[nn];
          if (which == 2)
            ((bf16*)C2)[(size_t)((b * 16 + hh) * 64 + d) * 2048 + tok] =
                __float2bfloat16(val);
          else if (which == 0)
            qk[(size_t)((b * 16 + hh) * 2048 + tok) * 64 + d] =
                __float2bfloat16(val * qscale);
          else
            qk[(size_t)((b * 16 + hh) * 2048 + tok) * 64 + d] =
                __float2bfloat16(val);
        }
      }
    }
  } else if constexpr (EPI == 4) {
    #pragma unroll
    for (int mi = 0; mi < 8; ++mi) {
      #pragma unroll
      for (int reg = 0; reg < 4; ++reg) {
        int m = m0 + wm + mi * 16 + qd * 4 + reg;
        #pragma unroll
        for (int ni = 0; ni < 4; ++ni) {
          int n = n0 + wn + ni * 16 + fr;
          float val = acc[mi][ni][reg] + bias0[n];
          ((bf16*)C0)[(size_t)m * N + n] = __float2bfloat16(gelu_f(val));
        }
      }
    }
  } else {  // EPI == 6
    bf16* pout = (bf16*)C0 + (size_t)blockIdx.z * M * N;
    #pragma unroll
    for (int mi = 0; mi < 8; ++mi) {
      #pragma unroll
      for (int reg = 0; reg < 4; ++reg) {
        int m = m0 + wm + mi * 16 + qd * 4 + reg;
        #pragma unroll
        for (int ni = 0; ni < 4; ++ni) {
          int n = n0 + wn + ni * 16 + fr;
          pout[(size_t)m * N + n] = __float2bfloat16(acc[mi][ni][reg]);
        }
      }
    }
  }
}

// ---------------- split-K reduce for MLP2: out = gelu(sum partials + b2) + out1
__global__ __launch_bounds__(256) void reduce_mlp2(
    const bf16* __restrict__ part, const float* __restrict__ b2,
    const float* __restrict__ out1, float* __restrict__ out) {
  const int row = blockIdx.x, t = threadIdx.x;
  const size_t base = (size_t)row * 1024 + t * 4;
  float sum[4] = {0.f, 0.f, 0.f, 0.f};
  #pragma unroll
  for (int kc = 0; kc < 4; ++kc) {
    ushort4 u = *(const ushort4*)(part + (size_t)kc * 4096 * 1024 + base);
    unsigned short us[4] = {u.x, u.y, u.z, u.w};
    #pragma unroll
    for (int j = 0; j < 4; ++j) {
      bf16 h;
      __builtin_memcpy(&h, &us[j], 2);
      sum[j] += __bfloat162float(h);
    }
  }
  float4 bv = ((const float4*)b2)[t];
  float4 rv = *(const float4*)(out1 + base);
  float4 o;
  o.x = gelu_f(sum[0] + bv.x) + rv.x;
  o.y = gelu_f(sum[1] + bv.y) + rv.y;
  o.z = gelu_f(sum[2] + bv.z) + rv.z;
  o.w = gelu_f(sum[3] + bv.w) + rv.w;
  *(float4*)(out + base) = o;
}

// ---------------- Flash attention, off-by-one softmax + head slimming
// q is PRESCALED by C=0.125*log2(e), so p = exp2(q.k) directly.
// S^T trick + QBLK=128 (two 16-row q sets per wave sharing K/V frag reads).
// ROUND-9 VERBATIM (63.0 µs, best measured) — reg-staged K/V, XOR-swizzled
// linear-64 Ks/Vs/Ps, XCD remap. FROZEN: rounds 4/5/10 restructures (DMA
// staging, global-direct, permlane P-exchange) all regressed. The residual
// 2.1M conflict-cycles are hidden (round-9 A/B: conflicts dropped, dur flat);
// the floor is the serial softmax VALU chain + latency at 2 blocks/CU.
__global__ __launch_bounds__(256) void attn_kernel(
    const bf16* __restrict__ q, const bf16* __restrict__ k,
    const bf16* __restrict__ vt, const float* __restrict__ slim,
    bf16* __restrict__ attn) {
  __shared__ __align__(16) bf16 Ks[64][64];
  __shared__ __align__(16) bf16 Vs[64][64];
  __shared__ __align__(16) bf16 Ps[4][2][16][64];

  const int t = threadIdx.x, lane = t & 63, w = t >> 6;
  const int fr = lane & 15, qd = lane >> 4;

  const int L = blockIdx.y * 16 + blockIdx.x;   // hw dispatch order (512 wgs)
  const int wg = (L & 7) * 64 + (L >> 3);       // XCD k -> contiguous 64 wgs
  const int bh = wg >> 4;                       // 4 heads per XCD chunk
  const int q0 = (wg & 15) * 128;

  const size_t bhbase = (size_t)bh * 2048 * 64;

  bf16x8 qf[2][2];
  #pragma unroll
  for (int s = 0; s < 2; ++s) {
    const int qrow = q0 + s * 64 + w * 16 + fr;
    const bf16* qp = q + bhbase + (size_t)qrow * 64 + qd * 8;
    qf[s][0] = *(const bf16x8*)qp;
    qf[s][1] = *(const bf16x8*)(qp + 32);
  }

  const int r0 = t >> 3, g0 = t & 7;
  const bf16* kbase = k + bhbase + (size_t)r0 * 64 + g0 * 8;
  const bf16* vbase = vt + bhbase + (size_t)r0 * 2048 + g0 * 8;

  // swizzled LDS write slot: (r0+32)&7 == r0&7, so one value serves both rows
  const int wsw = (g0 ^ (r0 & 7)) * 8;

  bf16x8 kreg0, kreg1, vreg0, vreg1;
  auto gload = [&](int j0) {
    kreg0 = *(const bf16x8*)(kbase + (size_t)j0 * 64);
    kreg1 = *(const bf16x8*)(kbase + (size_t)(j0 + 32) * 64);
    vreg0 = *(const bf16x8*)(vbase + j0);
    vreg1 = *(const bf16x8*)(vbase + (size_t)32 * 2048 + j0);
  };
  gload(0);

  f32x4 o_acc[2][4] = {};
  float m4[2][4] = {};
  float l4[2][4] = {};

  const int frs = fr & 7;
  const int so0 = (qd ^ frs) * 8;        // half 0: groups 0..3
  const int so1 = ((4 + qd) ^ frs) * 8;  // half 1: groups 4..7

  for (int it = 0; it < 32; ++it) {
    *(bf16x8*)&Ks[r0][wsw] = kreg0;
    *(bf16x8*)&Ks[r0 + 32][wsw] = kreg1;
    *(bf16x8*)&Vs[r0][wsw] = vreg0;
    *(bf16x8*)&Vs[r0 + 32][wsw] = vreg1;
    __syncthreads();
    if (it + 1 < 32) gload((it + 1) * 64);

    bf16x8 kf[4][2];
    #pragma unroll
    for (int nc = 0; nc < 4; ++nc) {
      const bf16* kr = &Ks[nc * 16 + fr][0];
      kf[nc][0] = *(const bf16x8*)(kr + so0);
      kf[nc][1] = *(const bf16x8*)(kr + so1);
    }

    f32x4 z[2][4];
    #pragma unroll
    for (int s = 0; s < 2; ++s)
      #pragma unroll
      for (int nc = 0; nc < 4; ++nc) {
        f32x4 zz = {};
        zz = __builtin_amdgcn_mfma_f32_16x16x32_bf16(kf[nc][0], qf[s][0], zz, 0, 0, 0);
        zz = __builtin_amdgcn_mfma_f32_16x16x32_bf16(kf[nc][1], qf[s][1], zz, 0, 0, 0);
        z[s][nc] = zz;
      }

    bf16x8 vf[4][2];
    #pragma unroll
    for (int dc = 0; dc < 4; ++dc) {
      const bf16* vr = &Vs[dc * 16 + fr][0];
      vf[dc][0] = *(const bf16x8*)(vr + so0);
      vf[dc][1] = *(const bf16x8*)(vr + so1);
    }

    #pragma unroll
    for (int s = 0; s < 2; ++s) {
      #pragma unroll
      for (int nc = 0; nc < 4; ++nc) {
        float p0 = __builtin_amdgcn_exp2f(z[s][nc][0]);
        float p1 = __builtin_amdgcn_exp2f(z[s][nc][1]);
        float p2 = __builtin_amdgcn_exp2f(z[s][nc][2]);
        float p3 = __builtin_amdgcn_exp2f(z[s][nc][3]);
        l4[s][nc] += (p0 + p1) + (p2 + p3);
        m4[s][nc] = fmaxf(m4[s][nc], fmaxf(fmaxf(p0, p1), fmaxf(p2, p3)));
        bf16x4 pk;
        pk[0] = (short)f2bfu(p0);
        pk[1] = (short)f2bfu(p1);
        pk[2] = (short)f2bfu(p2);
        pk[3] = (short)f2bfu(p3);
        // swizzled write: logical group g=2nc+(qd>>1), half (qd&1)
        const int pcol = (((2 * nc + (qd >> 1)) ^ frs) << 3) + ((qd & 1) << 2);
        *(bf16x4*)&Ps[w][s][fr][pcol] = pk;
      }

      bf16x8 pf0 = *(const bf16x8*)&Ps[w][s][fr][so0];
      bf16x8 pf1 = *(const bf16x8*)&Ps[w][s][fr][so1];
      #pragma unroll
      for (int dc = 0; dc < 4; ++dc) {
        o_acc[s][dc] = __builtin_amdgcn_mfma_f32_16x16x32_bf16(pf0, vf[dc][0], o_acc[s][dc], 0, 0, 0);
        o_acc[s][dc] = __builtin_amdgcn_mfma_f32_16x16x32_bf16(pf1, vf[dc][1], o_acc[s][dc], 0, 0, 0);
      }
    }
    __syncthreads();
  }

  const int b = bh >> 4, hh = bh & 15;
  const float sl_f = slim[hh];
  #pragma unroll
  for (int s = 0; s < 2; ++s) {
    float l_all = (l4[s][0] + l4[s][1]) + (l4[s][2] + l4[s][3]);
    float m_all = fmaxf(fmaxf(m4[s][0], m4[s][1]), fmaxf(m4[s][2], m4[s][3]));
    l_all += __shfl_xor(l_all, 16);
    m_all = fmaxf(m_all, __shfl_xor(m_all, 16));
    l_all += __shfl_xor(l_all, 32);
    m_all = fmaxf(m_all, __shfl_xor(m_all, 32));

    #pragma unroll
    for (int r = 0; r < 4; ++r) {
      float lr = __shfl(l_all, qd * 4 + r);
      float mr = __shfl(m_all, qd * 4 + r);
      float inv = sl_f / (mr + lr);
      int mrow = b * 2048 + q0 + s * 64 + w * 16 + qd * 4 + r;
      #pragma unroll
      for (int dc = 0; dc < 4; ++dc) {
        int col = hh * 64 + dc * 16 + fr;
        attn[(size_t)mrow * 1024 + col] = __float2bfloat16(o_acc[s][dc][r] * inv);
      }
    }
  }
}

extern "C" void kernel_launch(void* const* d_in, const int* in_sizes, int n_in,
                              void* d_out, int out_size, void* d_ws, size_t ws_size,
                              hipStream_t stream) {
  const float* x    = (const float*)d_in[0];
  const float* ln1g = (const float*)d_in[1];
  const float* ln1b = (const float*)d_in[2];
  const float* Wq   = (const float*)d_in[3];
  const float* bq   = (const float*)d_in[4];
  const float* Wk   = (const float*)d_in[5];
  const float* bk   = (const float*)d_in[6];
  const float* Wv   = (const float*)d_in[7];
  const float* bv   = (const float*)d_in[8];
  const float* Wo   = (const float*)d_in[9];
  const float* bo   = (const float*)d_in[10];
  const float* slim = (const float*)d_in[11];
  const float* ln2g = (const float*)d_in[12];
  const float* ln2b = (const float*)d_in[13];
  const float* W1   = (const float*)d_in[14];
  const float* b1   = (const float*)d_in[15];
  const float* W2   = (const float*)d_in[16];
  const float* b2   = (const float*)d_in[17];

  char* p = (char*)d_ws;
  auto take = [&](size_t nbytes) {
    char* r = p;
    p += (nbytes + 255) & ~(size_t)255;
    return r;
  };
  bf16* Wqkv_t = (bf16*)take((size_t)3072 * 1024 * 2);
  bf16* Wo_t = (bf16*)take((size_t)1024 * 1024 * 2);
  bf16* W1_t = (bf16*)take((size_t)4096 * 1024 * 2);
  bf16* W2_t = (bf16*)take((size_t)1024 * 4096 * 2);
  bf16* h1   = (bf16*)take((size_t)4096 * 1024 * 2);   // also partial[0]
  bf16* qb   = (bf16*)take((size_t)4096 * 1024 * 2);   // also partial[1]
  bf16* kb   = (bf16*)take((size_t)4096 * 1024 * 2);   // also partial[2]
  bf16* vtb  = (bf16*)take((size_t)4096 * 1024 * 2);   // also partial[3]
  bf16* attn = (bf16*)take((size_t)4096 * 1024 * 2);
  float* out1 = (float*)take((size_t)4096 * 1024 * 4);
  bf16* h2   = (bf16*)take((size_t)4096 * 1024 * 2);
  bf16* m1   = (bf16*)take((size_t)4096 * 4096 * 2);

  bf16* parts = h1;

  dim3 blk(256);
  dim3 blk512(512);

  // 4 square weight transposes in one launch (z = Wq,Wk,Wv,Wo)
  transpose_cast_qkvo<<<dim3(32, 32, 4), blk, 0, stream>>>(
      Wq, Wk, Wv, Wo, Wqkv_t, Wo_t);
  // W1 + W2 rectangular transposes in one launch (z = 0,1)
  transpose_cast_w12<<<dim3(4096, 1, 2), blk, 0, stream>>>(
      W1, W2, W1_t, W2_t);

  ln_kernel<<<4096, blk, 0, stream>>>(x, ln1g, ln1b, h1);

  // fused QKV: N = 3072 (q output prescaled by 0.125*log2e), 256² 4-phase
  gemm256<0><<<dim3(12, 16), blk512, 0, stream>>>(
      h1, Wqkv_t, bq, bk, bv, qb, kb, vtb, 4096, 3072, 1024);

  attn_kernel<<<dim3(16, 32), blk, 0, stream>>>(qb, kb, vtb, slim, attn);

  gemm_bf16<3><<<dim3(8, 32), blk, 0, stream>>>(
      attn, Wo_t, bo, x, out1, 4096, 1024, 1024);

  ln_kernel<<<4096, blk, 0, stream>>>(out1, ln2g, ln2b, h2);

  // MLP1: 256² 4-phase, 256 blocks = 1/CU
  gemm256<4><<<dim3(16, 16), blk512, 0, stream>>>(
      h2, W1_t, b1, nullptr, nullptr, m1, nullptr, nullptr, 4096, 4096, 1024);

  // MLP2 split-K=4: 256² 4-phase, 64 blocks x 4 K-chunks
  gemm256<6><<<dim3(4, 16, 4), blk512, 0, stream>>>(
      m1, W2_t, nullptr, nullptr, nullptr, parts, nullptr, nullptr,
      4096, 1024, 4096);
  reduce_mlp2<<<4096, blk, 0, stream>>>(parts, b2, out1, (float*)d_out);
}